// Round 17
// baseline (809.821 us; speedup 1.0000x reference)
//
#include <hip/hip_runtime.h>

typedef __attribute__((ext_vector_type(8))) __bf16 bf16x8;
typedef __attribute__((ext_vector_type(4))) float f32x4;
typedef __attribute__((ext_vector_type(8))) unsigned short ushort8;

#define DMODEL 1024
#define SEQ 1024
#define NLAYER 4

__device__ __forceinline__ unsigned short f2bf(float f) {
  unsigned u = __float_as_uint(f);
  u += 0x7fffu + ((u >> 16) & 1u);
  return (unsigned short)(u >> 16);
}

__device__ __forceinline__ float bf2f(unsigned short u) {
  return __uint_as_float((unsigned)u << 16);
}

__device__ __forceinline__ void async_copy16(const void* gsrc, const void* lds_dst) {
  __builtin_amdgcn_global_load_lds(
      (__attribute__((address_space(1))) void*)(unsigned long long)(gsrc),
      (__attribute__((address_space(3))) void*)(unsigned int)(unsigned long long)(lds_dst),
      16, 0, 0);
}

__device__ __forceinline__ f32x4 mfma16(bf16x8 a, bf16x8 b, f32x4 c) {
  return __builtin_amdgcn_mfma_f32_16x16x32_bf16(a, b, c, 0, 0, 0);
}

// ---------------- fused preprocessing (unchanged from R16) ----------------
__global__ __launch_bounds__(256) void preproc_kernel(
    const int* __restrict__ tok, const float* __restrict__ emb,
    const float* __restrict__ Wq, const float* __restrict__ Wk,
    const float* __restrict__ Wv, const float* __restrict__ Wo,
    const float* __restrict__ W1, const float* __restrict__ W2,
    const float* __restrict__ bq, const float* __restrict__ bk,
    const float* __restrict__ bv,
    unsigned short* __restrict__ wqkv_t, unsigned short* __restrict__ wo_t,
    unsigned short* __restrict__ w1_t, unsigned short* __restrict__ w2_t,
    float* __restrict__ qkvb, unsigned short* __restrict__ xb) {
  __shared__ unsigned short tileT[64 * 136];
  const int bid = blockIdx.x;
  const int tid = threadIdx.x;
  if (bid < 6144) {
    const float* src; unsigned short* dst; size_t R, C; int tx, ty;
    if (bid < 2048) {
      int w = bid >> 9, z = (bid >> 7) & 3, tl = bid & 127;
      tx = tl & 15; ty = tl >> 4; R = 1024; C = 1024;
      if (w == 0)      { src = Wq + (size_t)z * 1048576; dst = wqkv_t + (size_t)z * 3145728; }
      else if (w == 1) { src = Wk + (size_t)z * 1048576; dst = wqkv_t + (size_t)z * 3145728 + 1048576; }
      else if (w == 2) { src = Wv + (size_t)z * 1048576; dst = wqkv_t + (size_t)z * 3145728 + 2097152; }
      else             { src = Wo + (size_t)z * 1048576; dst = wo_t + (size_t)z * 1048576; }
    } else if (bid < 4096) {
      int t = bid - 2048, z = t >> 9, tl = t & 511;
      tx = tl & 63; ty = tl >> 6; R = 1024; C = 4096;
      src = W1 + (size_t)z * 4194304; dst = w1_t + (size_t)z * 4194304;
    } else {
      int t = bid - 4096, z = t >> 9, tl = t & 511;
      tx = tl & 15; ty = tl >> 4; R = 4096; C = 1024;
      src = W2 + (size_t)z * 4194304; dst = w2_t + (size_t)z * 4194304;
    }
    const int c0 = tx * 64, r0 = ty * 128;
    const int s16 = tid & 15, hi = tid >> 4;
#pragma unroll
    for (int it = 0; it < 8; ++it) {
      const int r = it * 16 + hi;
      f32x4 v = __builtin_nontemporal_load(
          (const f32x4*)(src + (size_t)(r0 + r) * C + c0 + s16 * 4));
#pragma unroll
      for (int j = 0; j < 4; ++j) {
        const int c = s16 * 4 + j;
        tileT[c * 136 + (r ^ ((c & 7) << 3))] = f2bf(v[j]);
      }
    }
    __syncthreads();
#pragma unroll
    for (int p = 0; p < 4; ++p) {
      const int c = p * 16 + hi;
      ushort8 o = *(const ushort8*)&tileT[c * 136 + 8 * (s16 ^ (c & 7))];
      *(ushort8*)(dst + (size_t)(c0 + c) * R + r0 + s16 * 8) = o;
    }
  } else if (bid < 10240) {
    const int row = bid - 6144;
    const int t = row & (SEQ - 1);
    const int tk = tok[row];
    const int col = tid * 4;
    float4 e = *(const float4*)(emb + (size_t)tk * DMODEL + col);
    const float c = -9.21034037197618f / (float)DMODEL;
    float d0 = __expf((float)(col)*c);
    float d1 = __expf((float)(col + 2) * c);
    float a0 = (float)t * d0, a1 = (float)t * d1;
    e.x += sinf(a0); e.y += cosf(a0); e.z += sinf(a1); e.w += cosf(a1);
    ushort4 ub;
    ub.x = f2bf(e.x); ub.y = f2bf(e.y); ub.z = f2bf(e.z); ub.w = f2bf(e.w);
    *(ushort4*)(xb + (size_t)row * DMODEL + col) = ub;
  } else {
    int i = (bid - 10240) * 256 + tid;
    if (i < NLAYER * 3072) {
      int l = i / 3072, j = i % 3072;
      float v = (j < 1024) ? bq[l * 1024 + j]
              : (j < 2048) ? bk[l * 1024 + j - 1024]
                           : bv[l * 1024 + j - 2048];
      qkvb[i] = v;
    }
  }
}

// ================= 256x256 8-phase GEMM (unchanged) =================
#define G256_PHASE(BUF, MH, NH, STAGE_STMT, VM)                                   \
  {                                                                               \
    if (NH == 0) {                                                                \
      _Pragma("unroll") for (int fm = 0; fm < 4; ++fm)                            \
      _Pragma("unroll") for (int kk = 0; kk < 2; ++kk) {                          \
        int row = wr * 64 + fm * 16 + lr;                                         \
        int cb = (kk * 64 + g * 16) ^ ((row & 4) ? 32 : 0) ^ ((row & 8) ? 64 : 0);\
        af[fm][kk] = *(const bf16x8*)((const char*)&As[BUF][MH][0] + row * 128 + cb); \
      }                                                                           \
    }                                                                             \
    _Pragma("unroll") for (int fn = 0; fn < 2; ++fn)                              \
    _Pragma("unroll") for (int kk = 0; kk < 2; ++kk) {                            \
      int row = wc * 32 + fn * 16 + lr;                                           \
      int cb = (kk * 64 + g * 16) ^ ((row & 4) ? 32 : 0) ^ ((row & 8) ? 64 : 0);  \
      bfr[fn][kk] = *(const bf16x8*)((const char*)&Bs[BUF][NH][0] + row * 128 + cb); \
    }                                                                             \
    STAGE_STMT;                                                                   \
    if (VM == 1) asm volatile("s_waitcnt vmcnt(4)" ::: "memory");                 \
    if (VM == 2) asm volatile("s_waitcnt vmcnt(0)" ::: "memory");                 \
    asm volatile("s_barrier" ::: "memory");                                       \
    asm volatile("s_waitcnt lgkmcnt(0)" ::: "memory");                            \
    __builtin_amdgcn_s_setprio(1);                                                \
    _Pragma("unroll") for (int fm = 0; fm < 4; ++fm)                              \
    _Pragma("unroll") for (int fn = 0; fn < 2; ++fn)                              \
    _Pragma("unroll") for (int kk = 0; kk < 2; ++kk)                              \
      acc[MH][fm][NH][fn] = mfma16(af[fm][kk], bfr[fn][kk], acc[MH][fm][NH][fn]); \
    __builtin_amdgcn_s_setprio(0);                                                \
    asm volatile("s_barrier" ::: "memory");                                       \
  }

template <int QKV>
__global__ __launch_bounds__(512, 1) void gemm256(
    const unsigned short* __restrict__ A, const unsigned short* __restrict__ Bt,
    const float* __restrict__ bias, unsigned short* __restrict__ Cb,
    unsigned short* __restrict__ Cb2, int N) {
  __shared__ __align__(16) unsigned short As[2][2][8192];
  __shared__ __align__(16) unsigned short Bs[2][2][8192];
  constexpr int NK = 16;
  constexpr int NI = 8;

  const int tid = threadIdx.x;
  const int wid = tid >> 6, l = tid & 63;
  const int lr = l & 15, g = l >> 4;
  const int wr = wid >> 2, wc = wid & 3;

  const int gx = gridDim.x, nwg = gx * gridDim.y;
  int bid = blockIdx.y * gx + blockIdx.x;
  const int cpx = nwg >> 3;
  bid = (bid & 7) * cpx + (bid >> 3);
  const int rm = (bid / gx) * 256, rn = (bid % gx) * 256;

  const int kOff = ((l & 7) * 8) ^ ((l & 32) ? 16 : 0) ^ ((wid & 1) ? 32 : 0);
  const int rOff = wid * 8 + (l >> 3);

  auto stA = [&](int buf, int half, int t) {
#pragma unroll
    for (int r2 = 0; r2 < 2; ++r2) {
      const unsigned short* gs =
          A + (size_t)(rm + half * 128 + r2 * 64 + rOff) * 1024 + t * 64 + kOff;
      async_copy16(gs, &As[buf][half][r2 * 4096 + wid * 512]);
    }
  };
  auto stB = [&](int buf, int half, int t) {
#pragma unroll
    for (int r2 = 0; r2 < 2; ++r2) {
      const unsigned short* gs =
          Bt + (size_t)(rn + half * 128 + r2 * 64 + rOff) * 1024 + t * 64 + kOff;
      async_copy16(gs, &Bs[buf][half][r2 * 4096 + wid * 512]);
    }
  };

  f32x4 acc[2][4][2][2] = {};
  bf16x8 af[4][2], bfr[2][2];

  stA(0, 0, 0); stA(0, 1, 0); stB(0, 0, 0); stB(0, 1, 0);
  stA(1, 0, 1); stB(1, 0, 1);
  asm volatile("s_waitcnt vmcnt(4)" ::: "memory");
  asm volatile("s_barrier" ::: "memory");

  for (int i = 0; i < NI - 1; ++i) {
    const int t1 = 2 * i + 1, t2 = 2 * i + 2, t3 = 2 * i + 3;
    G256_PHASE(0, 0, 0, { stA(1, 1, t1); }, 0)
    G256_PHASE(0, 0, 1, { stB(1, 1, t1); }, 0)
    G256_PHASE(0, 1, 0, { stA(0, 0, t2); }, 0)
    G256_PHASE(0, 1, 1, { stB(0, 0, t2); }, 1)
    G256_PHASE(1, 0, 0, { stA(0, 1, t2); }, 0)
    G256_PHASE(1, 0, 1, { stB(0, 1, t2); }, 0)
    G256_PHASE(1, 1, 0, { if (t3 < NK) stA(1, 0, t3); }, 0)
    G256_PHASE(1, 1, 1, { if (t3 < NK) stB(1, 0, t3); }, 1)
  }
  {
    const int t1 = NK - 1;
    G256_PHASE(0, 0, 0, { stA(1, 1, t1); }, 0)
    G256_PHASE(0, 0, 1, { stB(1, 1, t1); }, 0)
    G256_PHASE(0, 1, 0, {}, 0)
    G256_PHASE(0, 1, 1, {}, 2)
    G256_PHASE(1, 0, 0, {}, 0)
    G256_PHASE(1, 0, 1, {}, 0)
    G256_PHASE(1, 1, 0, {}, 0)
    G256_PHASE(1, 1, 1, {}, 0)
  }

#pragma unroll
  for (int mh = 0; mh < 2; ++mh)
#pragma unroll
    for (int nh = 0; nh < 2; ++nh)
#pragma unroll
      for (int fn = 0; fn < 2; ++fn) {
        const int col = rn + nh * 128 + wc * 32 + fn * 16 + lr;
        const float bv = bias[col];
        if (QKV && col >= 2048) {
#pragma unroll
          for (int fm = 0; fm < 4; ++fm) {
            const int row0 = rm + mh * 128 + wr * 64 + fm * 16 + g * 4;
            ushort4 vv;
            vv.x = f2bf(acc[mh][fm][nh][fn][0] + bv);
            vv.y = f2bf(acc[mh][fm][nh][fn][1] + bv);
            vv.z = f2bf(acc[mh][fm][nh][fn][2] + bv);
            vv.w = f2bf(acc[mh][fm][nh][fn][3] + bv);
            *(ushort4*)(Cb2 + (size_t)(col - 2048) * 4096 + row0) = vv;
          }
        } else {
          const float sc = (QKV && col < 1024) ? 0.18033688011112042f : 1.0f;
          const int ldc = QKV ? 2048 : N;
#pragma unroll
          for (int fm = 0; fm < 4; ++fm)
#pragma unroll
            for (int r = 0; r < 4; ++r) {
              const int row = rm + mh * 128 + wr * 64 + fm * 16 + g * 4 + r;
              float v = (acc[mh][fm][nh][fn][r] + bv) * sc;
              if (!QKV) v = fmaxf(v, 0.0f);
              Cb[(size_t)row * ldc + col] = f2bf(v);
            }
        }
      }
}

// ---------------- N=1024 GEMM v4 (Wo, FFN2): gemm256 phase schedule at 128² ------
// 2 phases/K-step (output halves fm0-1 / fm2-3), triple-buffered LDS (96KB),
// stages issued a FULL K-step ahead (stA(t+2)@pA, stB(t+2)@pB), one vmcnt(4)
// per K-step at pB draining stage(t+1). Ledger: reads of buf[t%3] need stage(t),
// published by pB(t-1)'s vmcnt(4) (outstanding = sA/sB(t+1) = exactly 4 loads);
// stages target (t+2)%3 == (t-1)%3, readers closed at pB(t-1) end barrier.
// Tail: vmcnt(0) at pB(nk-2); nothing at nk-1.
__global__ __launch_bounds__(512, 1) void gemm_bf16w(
    const unsigned short* __restrict__ A, const unsigned short* __restrict__ Bt,
    const float* __restrict__ bias, unsigned short* __restrict__ Cb,
    const unsigned short* __restrict__ Xres, int N, int K) {
  __shared__ __align__(16) unsigned short As[3][8192];
  __shared__ __align__(16) unsigned short Bs[3][8192];
  const int tid = threadIdx.x;
  const int wid = tid >> 6, l = tid & 63, lr = l & 15, g = l >> 4;
  const int wr = wid >> 2, wc = wid & 3;
  const int d = blockIdx.y * 8 + blockIdx.x;
  const int xcd = d & 7, slot = d >> 3;
  const int bandsPerXcd = gridDim.y >> 3;
  const int by = xcd * bandsPerXcd + (slot >> 3);
  const int bx = slot & 7;
  const int rm = by * 128, rn = bx * 128;
  const int nk = K >> 6;

  const int kOff = ((l & 7) * 8) ^ ((l & 32) ? 16 : 0) ^ ((wid & 1) ? 32 : 0);
  const int rOff = wid * 8 + (l >> 3);

  auto stA = [&](int buf, int t) {
#pragma unroll
    for (int r2 = 0; r2 < 2; ++r2) {
      const unsigned short* ga =
          A + (size_t)(rm + r2 * 64 + rOff) * K + t * 64 + kOff;
      async_copy16(ga, &As[buf][r2 * 4096 + wid * 512]);
    }
  };
  auto stB = [&](int buf, int t) {
#pragma unroll
    for (int r2 = 0; r2 < 2; ++r2) {
      const unsigned short* gb =
          Bt + (size_t)(rn + r2 * 64 + rOff) * K + t * 64 + kOff;
      async_copy16(gb, &Bs[buf][r2 * 4096 + wid * 512]);
    }
  };

  f32x4 acc[4][2] = {};
  bf16x8 af[4][2], bfr[2][2];

  // prologue: tiles 0 and 1 staged; drain tile 0 (leave tile 1's 4 in flight)
  stA(0, 0); stB(0, 0);
  stA(1, 1); stB(1, 1);
  asm volatile("s_waitcnt vmcnt(4)" ::: "memory");
  asm volatile("s_barrier" ::: "memory");

  for (int t = 0; t < nk; ++t) {
    const int cur = t % 3;
    // ---- phase A: output rows fm 0-1 ----
#pragma unroll
    for (int fm = 0; fm < 2; ++fm)
#pragma unroll
      for (int kk = 0; kk < 2; ++kk) {
        int row = wr * 64 + fm * 16 + lr;
        int cb = (kk * 64 + g * 16) ^ ((row & 4) ? 32 : 0) ^ ((row & 8) ? 64 : 0);
        af[fm][kk] = *(const bf16x8*)((const char*)&As[cur][0] + row * 128 + cb);
      }
#pragma unroll
    for (int fn = 0; fn < 2; ++fn)
#pragma unroll
      for (int kk = 0; kk < 2; ++kk) {
        int row = wc * 32 + fn * 16 + lr;
        int cb = (kk * 64 + g * 16) ^ ((row & 4) ? 32 : 0) ^ ((row & 8) ? 64 : 0);
        bfr[fn][kk] = *(const bf16x8*)((const char*)&Bs[cur][0] + row * 128 + cb);
      }
    if (t + 2 < nk) stA((t + 2) % 3, t + 2);
    asm volatile("s_barrier" ::: "memory");
    asm volatile("s_waitcnt lgkmcnt(0)" ::: "memory");
    __builtin_amdgcn_sched_barrier(0);
    __builtin_amdgcn_s_setprio(1);
#pragma unroll
    for (int fm = 0; fm < 2; ++fm)
#pragma unroll
      for (int fn = 0; fn < 2; ++fn)
#pragma unroll
        for (int kk = 0; kk < 2; ++kk)
          acc[fm][fn] = mfma16(af[fm][kk], bfr[fn][kk], acc[fm][fn]);
    __builtin_amdgcn_s_setprio(0);
    asm volatile("s_barrier" ::: "memory");
    // ---- phase B: output rows fm 2-3 ----
#pragma unroll
    for (int fm = 2; fm < 4; ++fm)
#pragma unroll
      for (int kk = 0; kk < 2; ++kk) {
        int row = wr * 64 + fm * 16 + lr;
        int cb = (kk * 64 + g * 16) ^ ((row & 4) ? 32 : 0) ^ ((row & 8) ? 64 : 0);
        af[fm][kk] = *(const bf16x8*)((const char*)&As[cur][0] + row * 128 + cb);
      }
    if (t + 2 < nk) {
      stB((t + 2) % 3, t + 2);
      asm volatile("s_waitcnt vmcnt(4)" ::: "memory");
    } else if (t + 1 < nk) {
      asm volatile("s_waitcnt vmcnt(0)" ::: "memory");
    }
    asm volatile("s_barrier" ::: "memory");
    asm volatile("s_waitcnt lgkmcnt(0)" ::: "memory");
    __builtin_amdgcn_sched_barrier(0);
    __builtin_amdgcn_s_setprio(1);
#pragma unroll
    for (int fm = 2; fm < 4; ++fm)
#pragma unroll
      for (int fn = 0; fn < 2; ++fn)
#pragma unroll
        for (int kk = 0; kk < 2; ++kk)
          acc[fm][fn] = mfma16(af[fm][kk], bfr[fn][kk], acc[fm][fn]);
    __builtin_amdgcn_s_setprio(0);
    asm volatile("s_barrier" ::: "memory");
  }

  const int row0 = rm + wr * 64 + g * 4;
  const int col0 = rn + wc * 32 + lr;
#pragma unroll
  for (int fn = 0; fn < 2; ++fn) {
    const int col = col0 + fn * 16;
    const float bv = bias[col];
#pragma unroll
    for (int fm = 0; fm < 4; ++fm)
#pragma unroll
      for (int r = 0; r < 4; ++r) {
        const int row = row0 + fm * 16 + r;
        float v = acc[fm][fn][r] + bv + bf2f(Xres[(size_t)row * N + col]);
        Cb[(size_t)row * N + col] = f2bf(v);
      }
  }
}

// ---------------- fused causal attention v2 (exact R14/R16 winner) ----------------
__global__ __launch_bounds__(256) void attn_kernel(
    const unsigned short* __restrict__ qk, const unsigned short* __restrict__ Vt,
    unsigned short* __restrict__ out) {
  __shared__ __align__(16) unsigned short Ks[2][64 * 64];
  __shared__ __align__(16) unsigned short Vs[2][64 * 64];
  __shared__ unsigned short Pl[4][32 * 72];
  const int tid = threadIdx.x;
  const int w = tid >> 6, l = tid & 63, lr = l & 15, g = l >> 4;
  const int bh = blockIdx.x;
  const int b = bh >> 4, h = bh & 15;
  const int byy = blockIdx.y;
  const int qblk = (byy < 4) ? (7 - byy) : (byy - 4);  // CU pairs sum to 7
  const int qb0 = qblk * 128 + w * 32;
  const size_t rowBase = (size_t)b * SEQ;
  const int cq = h * 64, ck = 1024 + h * 64;
  const int NTb = 2 * qblk + 2;

  const int sOff = ((l & 7) * 8) ^ ((l & 32) ? 16 : 0);
  const int sRow = l >> 3;

  auto stageKV = [&](int buf, int t) {
#pragma unroll
    for (int j = 0; j < 2; ++j) {
      const int row = w * 16 + j * 8 + sRow;
      const int off = sOff ^ (j ? 32 : 0);
      const unsigned short* gk =
          qk + (rowBase + t * 64 + row) * 2048 + ck + off;
      async_copy16(gk, &Ks[buf][(w * 16 + j * 8) * 64]);
      const unsigned short* gv =
          Vt + (size_t)(h * 64 + row) * 4096 + b * 1024 + t * 64 + off;
      async_copy16(gv, &Vs[buf][(w * 16 + j * 8) * 64]);
    }
  };

  bf16x8 aq[2][2];
#pragma unroll
  for (int qf = 0; qf < 2; ++qf)
#pragma unroll
    for (int ks = 0; ks < 2; ++ks)
      aq[qf][ks] = *(const bf16x8*)(qk + (rowBase + qb0 + qf * 16 + lr) * 2048 +
                                    cq + ks * 32 + g * 8);

  f32x4 o[2][4] = {};
  float l_[2][4] = {};

  const int rdswz = ((lr & 4) ? 16 : 0) ^ ((lr & 8) ? 32 : 0);

  stageKV(0, 0);
  asm volatile("s_waitcnt vmcnt(0)" ::: "memory");
  asm volatile("s_barrier" ::: "memory");

  for (int kt = 0; kt < NTb; ++kt) {
    const int k0 = kt * 64;
    const int cur = kt & 1;
    if (kt + 1 < NTb) stageKV(cur ^ 1, kt + 1);
    bf16x8 kf[4][2];
#pragma unroll
    for (int kg = 0; kg < 4; ++kg)
#pragma unroll
      for (int ks = 0; ks < 2; ++ks)
        kf[kg][ks] = *(const bf16x8*)&Ks[cur][(kg * 16 + lr) * 64 +
                                             ((ks * 32 + g * 8) ^ rdswz)];
    f32x4 s[2][4] = {};
#pragma unroll
    for (int kg = 0; kg < 4; ++kg)
#pragma unroll
      for (int qf = 0; qf < 2; ++qf) {
        s[qf][kg] = mfma16(aq[qf][0], kf[kg][0], s[qf][kg]);
        s[qf][kg] = mfma16(aq[qf][1], kf[kg][1], s[qf][kg]);
      }
    if (k0 + 63 <= qb0) {
#pragma unroll
      for (int qf = 0; qf < 2; ++qf)
#pragma unroll
        for (int r = 0; r < 4; ++r) {
          float e0 = exp2f(s[qf][0][r]);
          float e1 = exp2f(s[qf][1][r]);
          float e2 = exp2f(s[qf][2][r]);
          float e3 = exp2f(s[qf][3][r]);
          l_[qf][r] += (e0 + e1) + (e2 + e3);
          unsigned short* pr = &Pl[w][(qf * 16 + g * 4 + r) * 72];
          pr[lr] = f2bf(e0);
          pr[16 + lr] = f2bf(e1);
          pr[32 + lr] = f2bf(e2);
          pr[48 + lr] = f2bf(e3);
        }
    } else {
#pragma unroll
      for (int qf = 0; qf < 2; ++qf)
#pragma unroll
        for (int r = 0; r < 4; ++r) {
          const int q = qb0 + qf * 16 + g * 4 + r;
          float e0 = (k0 + lr <= q) ? exp2f(s[qf][0][r]) : 0.0f;
          float e1 = (k0 + 16 + lr <= q) ? exp2f(s[qf][1][r]) : 0.0f;
          float e2 = (k0 + 32 + lr <= q) ? exp2f(s[qf][2][r]) : 0.0f;
          float e3 = (k0 + 48 + lr <= q) ? exp2f(s[qf][3][r]) : 0.0f;
          l_[qf][r] += (e0 + e1) + (e2 + e3);
          unsigned short* pr = &Pl[w][(qf * 16 + g * 4 + r) * 72];
          pr[lr] = f2bf(e0);
          pr[16 + lr] = f2bf(e1);
          pr[32 + lr] = f2bf(e2);
          pr[48 + lr] = f2bf(e3);
        }
    }
    asm volatile("s_waitcnt lgkmcnt(0)" ::: "memory");
    __builtin_amdgcn_sched_barrier(0);
    bf16x8 pa[2][2];
#pragma unroll
    for (int qf = 0; qf < 2; ++qf)
#pragma unroll
      for (int kc = 0; kc < 2; ++kc)
        pa[qf][kc] = *(const bf16x8*)&Pl[w][(qf * 16 + lr) * 72 + kc * 32 + g * 8];
    bf16x8 vf[4][2];
#pragma unroll
    for (int nbv = 0; nbv < 4; ++nbv)
#pragma unroll
      for (int ks = 0; ks < 2; ++ks)
        vf[nbv][ks] = *(const bf16x8*)&Vs[cur][(nbv * 16 + lr) * 64 +
                                               ((ks * 32 + g * 8) ^ rdswz)];
#pragma unroll
    for (int nbv = 0; nbv < 4; ++nbv)
#pragma unroll
      for (int qf = 0; qf < 2; ++qf) {
        o[qf][nbv] = mfma16(pa[qf][0], vf[nbv][0], o[qf][nbv]);
        o[qf][nbv] = mfma16(pa[qf][1], vf[nbv][1], o[qf][nbv]);
      }
    asm volatile("s_waitcnt vmcnt(0)" ::: "memory");
    asm volatile("s_barrier" ::: "memory");
  }
  float rinv[2][4];
#pragma unroll
  for (int qf = 0; qf < 2; ++qf)
#pragma unroll
    for (int r = 0; r < 4; ++r) {
      float t = l_[qf][r];
      t += __shfl_xor(t, 1, 64);
      t += __shfl_xor(t, 2, 64);
      t += __shfl_xor(t, 4, 64);
      t += __shfl_xor(t, 8, 64);
      rinv[qf][r] = __builtin_amdgcn_rcpf(t);
    }
#pragma unroll
  for (int qf = 0; qf < 2; ++qf)
#pragma unroll
    for (int nbv = 0; nbv < 4; ++nbv)
#pragma unroll
      for (int r = 0; r < 4; ++r) {
        float val = o[qf][nbv][r] * rinv[qf][r];
        out[(rowBase + qb0 + qf * 16 + g * 4 + r) * 1024 + h * 64 + nbv * 16 + lr] =
            f2bf(val);
      }
}

// ---------------- layernorm (unchanged from R16) ----------------
__global__ __launch_bounds__(256) void ln_kernel(
    const unsigned short* __restrict__ tin,
    const float* __restrict__ gam, const float* __restrict__ bet,
    unsigned short* __restrict__ xbf, float* __restrict__ out2) {
  const int w = threadIdx.x >> 6, lane = threadIdx.x & 63;
  const int row = blockIdx.x * 4 + w;
  const size_t base = (size_t)row * DMODEL;
  const int c0 = lane * 8;
  const int c1 = 512 + lane * 8;
  ushort8 u0 = *(const ushort8*)(tin + base + c0);
  ushort8 u1 = *(const ushort8*)(tin + base + c1);
  float v[16];
#pragma unroll
  for (int i = 0; i < 8; ++i) { v[i] = bf2f(u0[i]); v[8 + i] = bf2f(u1[i]); }
  float s = 0.0f, ss = 0.0f;
#pragma unroll
  for (int i = 0; i < 16; ++i) { s += v[i]; ss += v[i] * v[i]; }
#pragma unroll
  for (int msk = 32; msk; msk >>= 1) {
    s += __shfl_xor(s, msk, 64);
    ss += __shfl_xor(ss, msk, 64);
  }
  const float mean = s * (1.0f / DMODEL);
  const float var = ss * (1.0f / DMODEL) - mean * mean;
  const float inv = rsqrtf(var + 1e-5f);
  float gv[16], bv[16];
  *(float4*)(gv + 0) = *(const float4*)(gam + c0);
  *(float4*)(gv + 4) = *(const float4*)(gam + c0 + 4);
  *(float4*)(gv + 8) = *(const float4*)(gam + c1);
  *(float4*)(gv + 12) = *(const float4*)(gam + c1 + 4);
  *(float4*)(bv + 0) = *(const float4*)(bet + c0);
  *(float4*)(bv + 4) = *(const float4*)(bet + c0 + 4);
  *(float4*)(bv + 8) = *(const float4*)(bet + c1);
  *(float4*)(bv + 12) = *(const float4*)(bet + c1 + 4);
  float ov[16];
#pragma unroll
  for (int i = 0; i < 16; ++i) ov[i] = (v[i] - mean) * inv * gv[i] + bv[i];
  ushort8 o0, o1;
#pragma unroll
  for (int i = 0; i < 8; ++i) { o0[i] = f2bf(ov[i]); o1[i] = f2bf(ov[8 + i]); }
  *(ushort8*)(xbf + base + c0) = o0;
  *(ushort8*)(xbf + base + c1) = o1;
  if (out2) {
    *(float4*)(out2 + base + c0) = *(float4*)(ov + 0);
    *(float4*)(out2 + base + c0 + 4) = *(float4*)(ov + 4);
    *(float4*)(out2 + base + c1) = *(float4*)(ov + 8);
    *(float4*)(out2 + base + c1 + 4) = *(float4*)(ov + 12);
  }
}

extern "C" void kernel_launch(void* const* d_in, const int* in_sizes, int n_in,
                              void* d_out, int out_size, void* d_ws, size_t ws_size,
                              hipStream_t stream) {
  (void)in_sizes; (void)n_in; (void)out_size; (void)ws_size;
  const int* tok = (const int*)d_in[0];
  const float* emb = (const float*)d_in[1];
  const float* Wq = (const float*)d_in[2];
  const float* bq = (const float*)d_in[3];
  const float* Wk = (const float*)d_in[4];
  const float* bk = (const float*)d_in[5];
  const float* Wv = (const float*)d_in[6];
  const float* bv = (const float*)d_in[7];
  const float* Wo = (const float*)d_in[8];
  const float* bo = (const float*)d_in[9];
  const float* ln1g = (const float*)d_in[10];
  const float* ln1b = (const float*)d_in[11];
  const float* W1 = (const float*)d_in[12];
  const float* b1 = (const float*)d_in[13];
  const float* W2 = (const float*)d_in[14];
  const float* b2 = (const float*)d_in[15];
  const float* ln2g = (const float*)d_in[16];
  const float* ln2b = (const float*)d_in[17];

  char* ws = (char*)d_ws;
  size_t off = 0;
  auto alloc = [&](size_t bytes) {
    char* p = ws + off;
    off += (bytes + 255) & ~(size_t)255;
    return p;
  };
  unsigned short* wqkv_t = (unsigned short*)alloc((size_t)NLAYER * 3072 * 1024 * 2);
  unsigned short* wo_t = (unsigned short*)alloc((size_t)NLAYER * 1024 * 1024 * 2);
  unsigned short* w1_t = (unsigned short*)alloc((size_t)NLAYER * 4096 * 1024 * 2);
  unsigned short* w2_t = (unsigned short*)alloc((size_t)NLAYER * 1024 * 4096 * 2);
  float* qkvb = (float*)alloc((size_t)NLAYER * 3072 * 4);
  unsigned short* yb = (unsigned short*)alloc((size_t)4096 * 1024 * 2);
  unsigned short* xb = (unsigned short*)alloc((size_t)4096 * 1024 * 2);
  unsigned short* qkbuf = (unsigned short*)alloc((size_t)4096 * 2048 * 2);
  unsigned short* vt = (unsigned short*)alloc((size_t)1024 * 4096 * 2);
  unsigned short* attn = (unsigned short*)alloc((size_t)4096 * 1024 * 2);
  unsigned short* hb = (unsigned short*)alloc((size_t)4096 * 4096 * 2);

  preproc_kernel<<<dim3(10288), dim3(256), 0, stream>>>(
      tok, emb, Wq, Wk, Wv, Wo, W1, W2, bq, bk, bv,
      wqkv_t, wo_t, w1_t, w2_t, qkvb, xb);

  for (int l = 0; l < NLAYER; ++l) {
    gemm256<1><<<dim3(12, 16), dim3(512), 0, stream>>>(
        xb, wqkv_t + (size_t)l * 3145728, qkvb + l * 3072, qkbuf, vt, 3072);
    attn_kernel<<<dim3(64, 8), dim3(256), 0, stream>>>(qkbuf, vt, attn);
    gemm_bf16w<<<dim3(8, 32), dim3(512), 0, stream>>>(
        attn, wo_t + (size_t)l * 1048576, bo + l * 1024, yb, xb, 1024, 1024);
    ln_kernel<<<dim3(1024), dim3(256), 0, stream>>>(
        yb, ln1g + l * 1024, ln1b + l * 1024, xb, nullptr);
    gemm256<0><<<dim3(16, 16), dim3(512), 0, stream>>>(
        xb, w1_t + (size_t)l * 4194304, b1 + l * 4096, hb, nullptr, 4096);
    gemm_bf16w<<<dim3(8, 32), dim3(512), 0, stream>>>(
        hb, w2_t + (size_t)l * 4194304, b2 + l * 1024, yb, xb, 1024, 4096);
    ln_kernel<<<dim3(1024), dim3(256), 0, stream>>>(
        yb, ln2g + l * 1024, ln2b + l * 1024, xb,
        (l == NLAYER - 1) ? (float*)d_out : nullptr);
  }
}

// Round 18
// 796.093 us; speedup vs baseline: 1.0172x; 1.0172x over previous
//
#include <hip/hip_runtime.h>

typedef __attribute__((ext_vector_type(8))) __bf16 bf16x8;
typedef __attribute__((ext_vector_type(4))) float f32x4;
typedef __attribute__((ext_vector_type(8))) unsigned short ushort8;

#define DMODEL 1024
#define SEQ 1024
#define NLAYER 4

__device__ __forceinline__ unsigned short f2bf(float f) {
  unsigned u = __float_as_uint(f);
  u += 0x7fffu + ((u >> 16) & 1u);
  return (unsigned short)(u >> 16);
}

__device__ __forceinline__ float bf2f(unsigned short u) {
  return __uint_as_float((unsigned)u << 16);
}

__device__ __forceinline__ void async_copy16(const void* gsrc, const void* lds_dst) {
  __builtin_amdgcn_global_load_lds(
      (__attribute__((address_space(1))) void*)(unsigned long long)(gsrc),
      (__attribute__((address_space(3))) void*)(unsigned int)(unsigned long long)(lds_dst),
      16, 0, 0);
}

__device__ __forceinline__ f32x4 mfma16(bf16x8 a, bf16x8 b, f32x4 c) {
  return __builtin_amdgcn_mfma_f32_16x16x32_bf16(a, b, c, 0, 0, 0);
}

// ---------------- fused preprocessing ----------------
__global__ __launch_bounds__(256) void preproc_kernel(
    const int* __restrict__ tok, const float* __restrict__ emb,
    const float* __restrict__ Wq, const float* __restrict__ Wk,
    const float* __restrict__ Wv, const float* __restrict__ Wo,
    const float* __restrict__ W1, const float* __restrict__ W2,
    const float* __restrict__ bq, const float* __restrict__ bk,
    const float* __restrict__ bv,
    unsigned short* __restrict__ wqkv_t, unsigned short* __restrict__ wo_t,
    unsigned short* __restrict__ w1_t, unsigned short* __restrict__ w2_t,
    float* __restrict__ qkvb, unsigned short* __restrict__ xb) {
  __shared__ unsigned short tileT[64 * 136];
  const int bid = blockIdx.x;
  const int tid = threadIdx.x;
  if (bid < 6144) {
    const float* src; unsigned short* dst; size_t R, C; int tx, ty;
    if (bid < 2048) {
      int w = bid >> 9, z = (bid >> 7) & 3, tl = bid & 127;
      tx = tl & 15; ty = tl >> 4; R = 1024; C = 1024;
      if (w == 0)      { src = Wq + (size_t)z * 1048576; dst = wqkv_t + (size_t)z * 3145728; }
      else if (w == 1) { src = Wk + (size_t)z * 1048576; dst = wqkv_t + (size_t)z * 3145728 + 1048576; }
      else if (w == 2) { src = Wv + (size_t)z * 1048576; dst = wqkv_t + (size_t)z * 3145728 + 2097152; }
      else             { src = Wo + (size_t)z * 1048576; dst = wo_t + (size_t)z * 1048576; }
    } else if (bid < 4096) {
      int t = bid - 2048, z = t >> 9, tl = t & 511;
      tx = tl & 63; ty = tl >> 6; R = 1024; C = 4096;
      src = W1 + (size_t)z * 4194304; dst = w1_t + (size_t)z * 4194304;
    } else {
      int t = bid - 4096, z = t >> 9, tl = t & 511;
      tx = tl & 15; ty = tl >> 4; R = 4096; C = 1024;
      src = W2 + (size_t)z * 4194304; dst = w2_t + (size_t)z * 4194304;
    }
    const int c0 = tx * 64, r0 = ty * 128;
    const int s16 = tid & 15, hi = tid >> 4;
#pragma unroll
    for (int it = 0; it < 8; ++it) {
      const int r = it * 16 + hi;
      f32x4 v = __builtin_nontemporal_load(
          (const f32x4*)(src + (size_t)(r0 + r) * C + c0 + s16 * 4));
#pragma unroll
      for (int j = 0; j < 4; ++j) {
        const int c = s16 * 4 + j;
        tileT[c * 136 + (r ^ ((c & 7) << 3))] = f2bf(v[j]);
      }
    }
    __syncthreads();
#pragma unroll
    for (int p = 0; p < 4; ++p) {
      const int c = p * 16 + hi;
      ushort8 o = *(const ushort8*)&tileT[c * 136 + 8 * (s16 ^ (c & 7))];
      *(ushort8*)(dst + (size_t)(c0 + c) * R + r0 + s16 * 8) = o;
    }
  } else if (bid < 10240) {
    const int row = bid - 6144;
    const int t = row & (SEQ - 1);
    const int tk = tok[row];
    const int col = tid * 4;
    float4 e = *(const float4*)(emb + (size_t)tk * DMODEL + col);
    const float c = -9.21034037197618f / (float)DMODEL;
    float d0 = __expf((float)(col)*c);
    float d1 = __expf((float)(col + 2) * c);
    float a0 = (float)t * d0, a1 = (float)t * d1;
    e.x += sinf(a0); e.y += cosf(a0); e.z += sinf(a1); e.w += cosf(a1);
    ushort4 ub;
    ub.x = f2bf(e.x); ub.y = f2bf(e.y); ub.z = f2bf(e.z); ub.w = f2bf(e.w);
    *(ushort4*)(xb + (size_t)row * DMODEL + col) = ub;
  } else {
    int i = (bid - 10240) * 256 + tid;
    if (i < NLAYER * 3072) {
      int l = i / 3072, j = i % 3072;
      float v = (j < 1024) ? bq[l * 1024 + j]
              : (j < 2048) ? bk[l * 1024 + j - 1024]
                           : bv[l * 1024 + j - 2048];
      qkvb[i] = v;
    }
  }
}

// ================= 256x256 8-phase GEMM =================
#define G256_PHASE(BUF, MH, NH, STAGE_STMT, VM)                                   \
  {                                                                               \
    if (NH == 0) {                                                                \
      _Pragma("unroll") for (int fm = 0; fm < 4; ++fm)                            \
      _Pragma("unroll") for (int kk = 0; kk < 2; ++kk) {                          \
        int row = wr * 64 + fm * 16 + lr;                                         \
        int cb = (kk * 64 + g * 16) ^ ((row & 4) ? 32 : 0) ^ ((row & 8) ? 64 : 0);\
        af[fm][kk] = *(const bf16x8*)((const char*)&As[BUF][MH][0] + row * 128 + cb); \
      }                                                                           \
    }                                                                             \
    _Pragma("unroll") for (int fn = 0; fn < 2; ++fn)                              \
    _Pragma("unroll") for (int kk = 0; kk < 2; ++kk) {                            \
      int row = wc * 32 + fn * 16 + lr;                                           \
      int cb = (kk * 64 + g * 16) ^ ((row & 4) ? 32 : 0) ^ ((row & 8) ? 64 : 0);  \
      bfr[fn][kk] = *(const bf16x8*)((const char*)&Bs[BUF][NH][0] + row * 128 + cb); \
    }                                                                             \
    STAGE_STMT;                                                                   \
    if (VM == 1) asm volatile("s_waitcnt vmcnt(4)" ::: "memory");                 \
    if (VM == 2) asm volatile("s_waitcnt vmcnt(0)" ::: "memory");                 \
    asm volatile("s_barrier" ::: "memory");                                       \
    asm volatile("s_waitcnt lgkmcnt(0)" ::: "memory");                            \
    __builtin_amdgcn_s_setprio(1);                                                \
    _Pragma("unroll") for (int fm = 0; fm < 4; ++fm)                              \
    _Pragma("unroll") for (int fn = 0; fn < 2; ++fn)                              \
    _Pragma("unroll") for (int kk = 0; kk < 2; ++kk)                              \
      acc[MH][fm][NH][fn] = mfma16(af[fm][kk], bfr[fn][kk], acc[MH][fm][NH][fn]); \
    __builtin_amdgcn_s_setprio(0);                                                \
    asm volatile("s_barrier" ::: "memory");                                       \
  }

template <int QKV>
__global__ __launch_bounds__(512, 1) void gemm256(
    const unsigned short* __restrict__ A, const unsigned short* __restrict__ Bt,
    const float* __restrict__ bias, unsigned short* __restrict__ Cb,
    unsigned short* __restrict__ Cb2, int N) {
  __shared__ __align__(16) unsigned short As[2][2][8192];
  __shared__ __align__(16) unsigned short Bs[2][2][8192];
  constexpr int NK = 16;
  constexpr int NI = 8;

  const int tid = threadIdx.x;
  const int wid = tid >> 6, l = tid & 63;
  const int lr = l & 15, g = l >> 4;
  const int wr = wid >> 2, wc = wid & 3;

  const int gx = gridDim.x, nwg = gx * gridDim.y;
  int bid = blockIdx.y * gx + blockIdx.x;
  const int cpx = nwg >> 3;
  bid = (bid & 7) * cpx + (bid >> 3);
  const int rm = (bid / gx) * 256, rn = (bid % gx) * 256;

  const int kOff = ((l & 7) * 8) ^ ((l & 32) ? 16 : 0) ^ ((wid & 1) ? 32 : 0);
  const int rOff = wid * 8 + (l >> 3);

  auto stA = [&](int buf, int half, int t) {
#pragma unroll
    for (int r2 = 0; r2 < 2; ++r2) {
      const unsigned short* gs =
          A + (size_t)(rm + half * 128 + r2 * 64 + rOff) * 1024 + t * 64 + kOff;
      async_copy16(gs, &As[buf][half][r2 * 4096 + wid * 512]);
    }
  };
  auto stB = [&](int buf, int half, int t) {
#pragma unroll
    for (int r2 = 0; r2 < 2; ++r2) {
      const unsigned short* gs =
          Bt + (size_t)(rn + half * 128 + r2 * 64 + rOff) * 1024 + t * 64 + kOff;
      async_copy16(gs, &Bs[buf][half][r2 * 4096 + wid * 512]);
    }
  };

  f32x4 acc[2][4][2][2] = {};
  bf16x8 af[4][2], bfr[2][2];

  stA(0, 0, 0); stA(0, 1, 0); stB(0, 0, 0); stB(0, 1, 0);
  stA(1, 0, 1); stB(1, 0, 1);
  asm volatile("s_waitcnt vmcnt(4)" ::: "memory");
  asm volatile("s_barrier" ::: "memory");

  for (int i = 0; i < NI - 1; ++i) {
    const int t1 = 2 * i + 1, t2 = 2 * i + 2, t3 = 2 * i + 3;
    G256_PHASE(0, 0, 0, { stA(1, 1, t1); }, 0)
    G256_PHASE(0, 0, 1, { stB(1, 1, t1); }, 0)
    G256_PHASE(0, 1, 0, { stA(0, 0, t2); }, 0)
    G256_PHASE(0, 1, 1, { stB(0, 0, t2); }, 1)
    G256_PHASE(1, 0, 0, { stA(0, 1, t2); }, 0)
    G256_PHASE(1, 0, 1, { stB(0, 1, t2); }, 0)
    G256_PHASE(1, 1, 0, { if (t3 < NK) stA(1, 0, t3); }, 0)
    G256_PHASE(1, 1, 1, { if (t3 < NK) stB(1, 0, t3); }, 1)
  }
  {
    const int t1 = NK - 1;
    G256_PHASE(0, 0, 0, { stA(1, 1, t1); }, 0)
    G256_PHASE(0, 0, 1, { stB(1, 1, t1); }, 0)
    G256_PHASE(0, 1, 0, {}, 0)
    G256_PHASE(0, 1, 1, {}, 2)
    G256_PHASE(1, 0, 0, {}, 0)
    G256_PHASE(1, 0, 1, {}, 0)
    G256_PHASE(1, 1, 0, {}, 0)
    G256_PHASE(1, 1, 1, {}, 0)
  }

#pragma unroll
  for (int mh = 0; mh < 2; ++mh)
#pragma unroll
    for (int nh = 0; nh < 2; ++nh)
#pragma unroll
      for (int fn = 0; fn < 2; ++fn) {
        const int col = rn + nh * 128 + wc * 32 + fn * 16 + lr;
        const float bv = bias[col];
        if (QKV && col >= 2048) {
#pragma unroll
          for (int fm = 0; fm < 4; ++fm) {
            const int row0 = rm + mh * 128 + wr * 64 + fm * 16 + g * 4;
            ushort4 vv;
            vv.x = f2bf(acc[mh][fm][nh][fn][0] + bv);
            vv.y = f2bf(acc[mh][fm][nh][fn][1] + bv);
            vv.z = f2bf(acc[mh][fm][nh][fn][2] + bv);
            vv.w = f2bf(acc[mh][fm][nh][fn][3] + bv);
            *(ushort4*)(Cb2 + (size_t)(col - 2048) * 4096 + row0) = vv;
          }
        } else {
          const float sc = (QKV && col < 1024) ? 0.18033688011112042f : 1.0f;
          const int ldc = QKV ? 2048 : N;
#pragma unroll
          for (int fm = 0; fm < 4; ++fm)
#pragma unroll
            for (int r = 0; r < 4; ++r) {
              const int row = rm + mh * 128 + wr * 64 + fm * 16 + g * 4 + r;
              float v = (acc[mh][fm][nh][fn][r] + bv) * sc;
              if (!QKV) v = fmaxf(v, 0.0f);
              Cb[(size_t)row * ldc + col] = f2bf(v);
            }
        }
      }
}

// ---------------- N=1024 GEMM (Wo, FFN2) — R13/R16-winning loop ----------------
__global__ __launch_bounds__(512, 2) void gemm_bf16w(
    const unsigned short* __restrict__ A, const unsigned short* __restrict__ Bt,
    const float* __restrict__ bias, unsigned short* __restrict__ Cb,
    const unsigned short* __restrict__ Xres, int N, int K) {
  __shared__ __align__(16) unsigned short As[2][8192];
  __shared__ __align__(16) unsigned short Bs[2][8192];
  const int tid = threadIdx.x;
  const int wid = tid >> 6, l = tid & 63, lr = l & 15, g = l >> 4;
  const int wr = wid >> 2, wc = wid & 3;
  const int d = blockIdx.y * 8 + blockIdx.x;
  const int xcd = d & 7, slot = d >> 3;
  const int bandsPerXcd = gridDim.y >> 3;
  const int by = xcd * bandsPerXcd + (slot >> 3);
  const int bx = slot & 7;
  const int rm = by * 128, rn = bx * 128;
  const int nk = K >> 6;

  const int kOff = ((l & 7) * 8) ^ ((l & 32) ? 16 : 0) ^ ((wid & 1) ? 32 : 0);
  const int rOff = wid * 8 + (l >> 3);

  auto stage = [&](int buf, int t) {
#pragma unroll
    for (int r2 = 0; r2 < 2; ++r2) {
      const unsigned short* ga =
          A + (size_t)(rm + r2 * 64 + rOff) * K + t * 64 + kOff;
      async_copy16(ga, &As[buf][r2 * 4096 + wid * 512]);
      const unsigned short* gb =
          Bt + (size_t)(rn + r2 * 64 + rOff) * K + t * 64 + kOff;
      async_copy16(gb, &Bs[buf][r2 * 4096 + wid * 512]);
    }
  };

  f32x4 acc[4][2] = {};
  stage(0, 0);
  asm volatile("s_waitcnt vmcnt(0)" ::: "memory");
  asm volatile("s_barrier" ::: "memory");

  for (int t = 0; t < nk; ++t) {
    const int cur = t & 1;
    if (t + 1 < nk) stage(cur ^ 1, t + 1);
    bf16x8 af[4][2], bfr[2][2];
#pragma unroll
    for (int fm = 0; fm < 4; ++fm)
#pragma unroll
      for (int kk = 0; kk < 2; ++kk) {
        int row = wr * 64 + fm * 16 + lr;
        int cb = (kk * 64 + g * 16) ^ ((row & 4) ? 32 : 0) ^ ((row & 8) ? 64 : 0);
        af[fm][kk] = *(const bf16x8*)((const char*)&As[cur][0] + row * 128 + cb);
      }
#pragma unroll
    for (int fn = 0; fn < 2; ++fn)
#pragma unroll
      for (int kk = 0; kk < 2; ++kk) {
        int row = wc * 32 + fn * 16 + lr;
        int cb = (kk * 64 + g * 16) ^ ((row & 4) ? 32 : 0) ^ ((row & 8) ? 64 : 0);
        bfr[fn][kk] = *(const bf16x8*)((const char*)&Bs[cur][0] + row * 128 + cb);
      }
    asm volatile("s_waitcnt lgkmcnt(0)" ::: "memory");
    __builtin_amdgcn_sched_barrier(0);
    __builtin_amdgcn_s_setprio(1);
#pragma unroll
    for (int fm = 0; fm < 4; ++fm)
#pragma unroll
      for (int fn = 0; fn < 2; ++fn)
#pragma unroll
        for (int kk = 0; kk < 2; ++kk)
          acc[fm][fn] = mfma16(af[fm][kk], bfr[fn][kk], acc[fm][fn]);
    __builtin_amdgcn_s_setprio(0);
    asm volatile("s_waitcnt vmcnt(0)" ::: "memory");
    asm volatile("s_barrier" ::: "memory");
  }

  const int row0 = rm + wr * 64 + g * 4;
  const int col0 = rn + wc * 32 + lr;
#pragma unroll
  for (int fn = 0; fn < 2; ++fn) {
    const int col = col0 + fn * 16;
    const float bv = bias[col];
#pragma unroll
    for (int fm = 0; fm < 4; ++fm)
#pragma unroll
      for (int r = 0; r < 4; ++r) {
        const int row = row0 + fm * 16 + r;
        float v = acc[fm][fn][r] + bv + bf2f(Xres[(size_t)row * N + col]);
        Cb[(size_t)row * N + col] = f2bf(v);
      }
  }
}

// ---------------- fused causal attention v2 (R14/R16 winner) ----------------
__global__ __launch_bounds__(256) void attn_kernel(
    const unsigned short* __restrict__ qk, const unsigned short* __restrict__ Vt,
    unsigned short* __restrict__ out) {
  __shared__ __align__(16) unsigned short Ks[2][64 * 64];
  __shared__ __align__(16) unsigned short Vs[2][64 * 64];
  __shared__ unsigned short Pl[4][32 * 72];
  const int tid = threadIdx.x;
  const int w = tid >> 6, l = tid & 63, lr = l & 15, g = l >> 4;
  const int bh = blockIdx.x;
  const int b = bh >> 4, h = bh & 15;
  const int byy = blockIdx.y;
  const int qblk = (byy < 4) ? (7 - byy) : (byy - 4);  // CU pairs sum to 7
  const int qb0 = qblk * 128 + w * 32;
  const size_t rowBase = (size_t)b * SEQ;
  const int cq = h * 64, ck = 1024 + h * 64;
  const int NTb = 2 * qblk + 2;

  const int sOff = ((l & 7) * 8) ^ ((l & 32) ? 16 : 0);
  const int sRow = l >> 3;

  auto stageKV = [&](int buf, int t) {
#pragma unroll
    for (int j = 0; j < 2; ++j) {
      const int row = w * 16 + j * 8 + sRow;
      const int off = sOff ^ (j ? 32 : 0);
      const unsigned short* gk =
          qk + (rowBase + t * 64 + row) * 2048 + ck + off;
      async_copy16(gk, &Ks[buf][(w * 16 + j * 8) * 64]);
      const unsigned short* gv =
          Vt + (size_t)(h * 64 + row) * 4096 + b * 1024 + t * 64 + off;
      async_copy16(gv, &Vs[buf][(w * 16 + j * 8) * 64]);
    }
  };

  bf16x8 aq[2][2];
#pragma unroll
  for (int qf = 0; qf < 2; ++qf)
#pragma unroll
    for (int ks = 0; ks < 2; ++ks)
      aq[qf][ks] = *(const bf16x8*)(qk + (rowBase + qb0 + qf * 16 + lr) * 2048 +
                                    cq + ks * 32 + g * 8);

  f32x4 o[2][4] = {};
  float l_[2][4] = {};

  const int rdswz = ((lr & 4) ? 16 : 0) ^ ((lr & 8) ? 32 : 0);

  stageKV(0, 0);
  asm volatile("s_waitcnt vmcnt(0)" ::: "memory");
  asm volatile("s_barrier" ::: "memory");

  for (int kt = 0; kt < NTb; ++kt) {
    const int k0 = kt * 64;
    const int cur = kt & 1;
    if (kt + 1 < NTb) stageKV(cur ^ 1, kt + 1);
    bf16x8 kf[4][2];
#pragma unroll
    for (int kg = 0; kg < 4; ++kg)
#pragma unroll
      for (int ks = 0; ks < 2; ++ks)
        kf[kg][ks] = *(const bf16x8*)&Ks[cur][(kg * 16 + lr) * 64 +
                                             ((ks * 32 + g * 8) ^ rdswz)];
    f32x4 s[2][4] = {};
#pragma unroll
    for (int kg = 0; kg < 4; ++kg)
#pragma unroll
      for (int qf = 0; qf < 2; ++qf) {
        s[qf][kg] = mfma16(aq[qf][0], kf[kg][0], s[qf][kg]);
        s[qf][kg] = mfma16(aq[qf][1], kf[kg][1], s[qf][kg]);
      }
    if (k0 + 63 <= qb0) {
#pragma unroll
      for (int qf = 0; qf < 2; ++qf)
#pragma unroll
        for (int r = 0; r < 4; ++r) {
          float e0 = exp2f(s[qf][0][r]);
          float e1 = exp2f(s[qf][1][r]);
          float e2 = exp2f(s[qf][2][r]);
          float e3 = exp2f(s[qf][3][r]);
          l_[qf][r] += (e0 + e1) + (e2 + e3);
          unsigned short* pr = &Pl[w][(qf * 16 + g * 4 + r) * 72];
          pr[lr] = f2bf(e0);
          pr[16 + lr] = f2bf(e1);
          pr[32 + lr] = f2bf(e2);
          pr[48 + lr] = f2bf(e3);
        }
    } else {
#pragma unroll
      for (int qf = 0; qf < 2; ++qf)
#pragma unroll
        for (int r = 0; r < 4; ++r) {
          const int q = qb0 + qf * 16 + g * 4 + r;
          float e0 = (k0 + lr <= q) ? exp2f(s[qf][0][r]) : 0.0f;
          float e1 = (k0 + 16 + lr <= q) ? exp2f(s[qf][1][r]) : 0.0f;
          float e2 = (k0 + 32 + lr <= q) ? exp2f(s[qf][2][r]) : 0.0f;
          float e3 = (k0 + 48 + lr <= q) ? exp2f(s[qf][3][r]) : 0.0f;
          l_[qf][r] += (e0 + e1) + (e2 + e3);
          unsigned short* pr = &Pl[w][(qf * 16 + g * 4 + r) * 72];
          pr[lr] = f2bf(e0);
          pr[16 + lr] = f2bf(e1);
          pr[32 + lr] = f2bf(e2);
          pr[48 + lr] = f2bf(e3);
        }
    }
    asm volatile("s_waitcnt lgkmcnt(0)" ::: "memory");
    __builtin_amdgcn_sched_barrier(0);
    bf16x8 pa[2][2];
#pragma unroll
    for (int qf = 0; qf < 2; ++qf)
#pragma unroll
      for (int kc = 0; kc < 2; ++kc)
        pa[qf][kc] = *(const bf16x8*)&Pl[w][(qf * 16 + lr) * 72 + kc * 32 + g * 8];
    bf16x8 vf[4][2];
#pragma unroll
    for (int nbv = 0; nbv < 4; ++nbv)
#pragma unroll
      for (int ks = 0; ks < 2; ++ks)
        vf[nbv][ks] = *(const bf16x8*)&Vs[cur][(nbv * 16 + lr) * 64 +
                                               ((ks * 32 + g * 8) ^ rdswz)];
#pragma unroll
    for (int nbv = 0; nbv < 4; ++nbv)
#pragma unroll
      for (int qf = 0; qf < 2; ++qf) {
        o[qf][nbv] = mfma16(pa[qf][0], vf[nbv][0], o[qf][nbv]);
        o[qf][nbv] = mfma16(pa[qf][1], vf[nbv][1], o[qf][nbv]);
      }
    asm volatile("s_waitcnt vmcnt(0)" ::: "memory");
    asm volatile("s_barrier" ::: "memory");
  }
  float rinv[2][4];
#pragma unroll
  for (int qf = 0; qf < 2; ++qf)
#pragma unroll
    for (int r = 0; r < 4; ++r) {
      float t = l_[qf][r];
      t += __shfl_xor(t, 1, 64);
      t += __shfl_xor(t, 2, 64);
      t += __shfl_xor(t, 4, 64);
      t += __shfl_xor(t, 8, 64);
      rinv[qf][r] = __builtin_amdgcn_rcpf(t);
    }
#pragma unroll
  for (int qf = 0; qf < 2; ++qf)
#pragma unroll
    for (int nbv = 0; nbv < 4; ++nbv)
#pragma unroll
      for (int r = 0; r < 4; ++r) {
        float val = o[qf][nbv][r] * rinv[qf][r];
        out[(rowBase + qb0 + qf * 16 + g * 4 + r) * 1024 + h * 64 + nbv * 16 + lr] =
            f2bf(val);
      }
}

// ---------------- layernorm ----------------
__global__ __launch_bounds__(256) void ln_kernel(
    const unsigned short* __restrict__ tin,
    const float* __restrict__ gam, const float* __restrict__ bet,
    unsigned short* __restrict__ xbf, float* __restrict__ out2) {
  const int w = threadIdx.x >> 6, lane = threadIdx.x & 63;
  const int row = blockIdx.x * 4 + w;
  const size_t base = (size_t)row * DMODEL;
  const int c0 = lane * 8;
  const int c1 = 512 + lane * 8;
  ushort8 u0 = *(const ushort8*)(tin + base + c0);
  ushort8 u1 = *(const ushort8*)(tin + base + c1);
  float v[16];
#pragma unroll
  for (int i = 0; i < 8; ++i) { v[i] = bf2f(u0[i]); v[8 + i] = bf2f(u1[i]); }
  float s = 0.0f, ss = 0.0f;
#pragma unroll
  for (int i = 0; i < 16; ++i) { s += v[i]; ss += v[i] * v[i]; }
#pragma unroll
  for (int msk = 32; msk; msk >>= 1) {
    s += __shfl_xor(s, msk, 64);
    ss += __shfl_xor(ss, msk, 64);
  }
  const float mean = s * (1.0f / DMODEL);
  const float var = ss * (1.0f / DMODEL) - mean * mean;
  const float inv = rsqrtf(var + 1e-5f);
  float gv[16], bv[16];
  *(float4*)(gv + 0) = *(const float4*)(gam + c0);
  *(float4*)(gv + 4) = *(const float4*)(gam + c0 + 4);
  *(float4*)(gv + 8) = *(const float4*)(gam + c1);
  *(float4*)(gv + 12) = *(const float4*)(gam + c1 + 4);
  *(float4*)(bv + 0) = *(const float4*)(bet + c0);
  *(float4*)(bv + 4) = *(const float4*)(bet + c0 + 4);
  *(float4*)(bv + 8) = *(const float4*)(bet + c1);
  *(float4*)(bv + 12) = *(const float4*)(bet + c1 + 4);
  float ov[16];
#pragma unroll
  for (int i = 0; i < 16; ++i) ov[i] = (v[i] - mean) * inv * gv[i] + bv[i];
  ushort8 o0, o1;
#pragma unroll
  for (int i = 0; i < 8; ++i) { o0[i] = f2bf(ov[i]); o1[i] = f2bf(ov[8 + i]); }
  *(ushort8*)(xbf + base + c0) = o0;
  *(ushort8*)(xbf + base + c1) = o1;
  if (out2) {
    *(float4*)(out2 + base + c0) = *(float4*)(ov + 0);
    *(float4*)(out2 + base + c0 + 4) = *(float4*)(ov + 4);
    *(float4*)(out2 + base + c1) = *(float4*)(ov + 8);
    *(float4*)(out2 + base + c1 + 4) = *(float4*)(ov + 12);
  }
}

extern "C" void kernel_launch(void* const* d_in, const int* in_sizes, int n_in,
                              void* d_out, int out_size, void* d_ws, size_t ws_size,
                              hipStream_t stream) {
  (void)in_sizes; (void)n_in; (void)out_size; (void)ws_size;
  const int* tok = (const int*)d_in[0];
  const float* emb = (const float*)d_in[1];
  const float* Wq = (const float*)d_in[2];
  const float* bq = (const float*)d_in[3];
  const float* Wk = (const float*)d_in[4];
  const float* bk = (const float*)d_in[5];
  const float* Wv = (const float*)d_in[6];
  const float* bv = (const float*)d_in[7];
  const float* Wo = (const float*)d_in[8];
  const float* bo = (const float*)d_in[9];
  const float* ln1g = (const float*)d_in[10];
  const float* ln1b = (const float*)d_in[11];
  const float* W1 = (const float*)d_in[12];
  const float* b1 = (const float*)d_in[13];
  const float* W2 = (const float*)d_in[14];
  const float* b2 = (const float*)d_in[15];
  const float* ln2g = (const float*)d_in[16];
  const float* ln2b = (const float*)d_in[17];

  char* ws = (char*)d_ws;
  size_t off = 0;
  auto alloc = [&](size_t bytes) {
    char* p = ws + off;
    off += (bytes + 255) & ~(size_t)255;
    return p;
  };
  unsigned short* wqkv_t = (unsigned short*)alloc((size_t)NLAYER * 3072 * 1024 * 2);
  unsigned short* wo_t = (unsigned short*)alloc((size_t)NLAYER * 1024 * 1024 * 2);
  unsigned short* w1_t = (unsigned short*)alloc((size_t)NLAYER * 4096 * 1024 * 2);
  unsigned short* w2_t = (unsigned short*)alloc((size_t)NLAYER * 1024 * 4096 * 2);
  float* qkvb = (float*)alloc((size_t)NLAYER * 3072 * 4);
  unsigned short* yb = (unsigned short*)alloc((size_t)4096 * 1024 * 2);
  unsigned short* xb = (unsigned short*)alloc((size_t)4096 * 1024 * 2);
  unsigned short* qkbuf = (unsigned short*)alloc((size_t)4096 * 2048 * 2);
  unsigned short* vt = (unsigned short*)alloc((size_t)1024 * 4096 * 2);
  unsigned short* attn = (unsigned short*)alloc((size_t)4096 * 1024 * 2);
  unsigned short* hb = (unsigned short*)alloc((size_t)4096 * 4096 * 2);

  preproc_kernel<<<dim3(10288), dim3(256), 0, stream>>>(
      tok, emb, Wq, Wk, Wv, Wo, W1, W2, bq, bk, bv,
      wqkv_t, wo_t, w1_t, w2_t, qkvb, xb);

  for (int l = 0; l < NLAYER; ++l) {
    gemm256<1><<<dim3(12, 16), dim3(512), 0, stream>>>(
        xb, wqkv_t + (size_t)l * 3145728, qkvb + l * 3072, qkbuf, vt, 3072);
    attn_kernel<<<dim3(64, 8), dim3(256), 0, stream>>>(qkbuf, vt, attn);
    gemm_bf16w<<<dim3(8, 32), dim3(512), 0, stream>>>(
        attn, wo_t + (size_t)l * 1048576, bo + l * 1024, yb, xb, 1024, 1024);
    ln_kernel<<<dim3(1024), dim3(256), 0, stream>>>(
        yb, ln1g + l * 1024, ln1b + l * 1024, xb, nullptr);
    gemm256<0><<<dim3(16, 16), dim3(512), 0, stream>>>(
        xb, w1_t + (size_t)l * 4194304, b1 + l * 4096, hb, nullptr, 4096);
    gemm_bf16w<<<dim3(8, 32), dim3(512), 0, stream>>>(
        hb, w2_t + (size_t)l * 4194304, b2 + l * 1024, yb, xb, 1024, 4096);
    ln_kernel<<<dim3(1024), dim3(256), 0, stream>>>(
        yb, ln2g + l * 1024, ln2b + l * 1024, xb,
        (l == NLAYER - 1) ? (float*)d_out : nullptr);
  }
}